// Round 2
// baseline (1464.085 us; speedup 1.0000x reference)
//
#include <hip/hip_runtime.h>
#include <math.h>

#define NNODES 100000
#define NEDGES 1600000
#define NGRAPH 256
#define NCONV  3
#define TBL    2048
#define NB1    98          // ceil(100000/1024)
#define R_MIN_ 1.0f
#define R_MAX_ 6.0f

__device__ __forceinline__ float softplus_f(float x){
  return fmaxf(x, 0.f) + __logf(1.f + __expf(-fabsf(x)));
}
__device__ __forceinline__ float sigmoid_f(float x){
  return __builtin_amdgcn_rcpf(1.f + __expf(-x));
}

// ---------------- init: zero deg + graph accumulators ----------------
__global__ void k_init(int* deg, float* gsum, int* gcnt){
  int i = blockIdx.x*256 + threadIdx.x;
  if (i < NNODES) deg[i] = 0;
  if (i < NGRAPH){ gsum[i] = 0.f; gcnt[i] = 0; }
}

// ---------------- embedding gather ----------------
__global__ void k_embed(const int* __restrict__ numbers, const float* __restrict__ embed,
                        float* __restrict__ x){
  int i = blockIdx.x*256 + threadIdx.x;   // over N*64
  if (i >= NNODES*64) return;
  int n = i >> 6, c = i & 63;
  x[i] = embed[numbers[n]*64 + c];
}

// ---------------- CSR build ----------------
__global__ void k_hist(const int* __restrict__ src, int* deg){
  int e = blockIdx.x*256 + threadIdx.x;
  if (e < NEDGES) atomicAdd(&deg[src[e]], 1);
}

__global__ void k_scan1(const int* __restrict__ deg, int* __restrict__ offs, int* __restrict__ bsum){
  __shared__ int s[1024];
  int n = blockIdx.x*1024 + threadIdx.x;
  int v = (n < NNODES) ? deg[n] : 0;
  s[threadIdx.x] = v;
  __syncthreads();
  for (int d = 1; d < 1024; d <<= 1){
    int t = (threadIdx.x >= d) ? s[threadIdx.x - d] : 0;
    __syncthreads();
    s[threadIdx.x] += t;
    __syncthreads();
  }
  int incl = s[threadIdx.x];
  if (n < NNODES) offs[n] = incl - v;           // exclusive
  if (threadIdx.x == 1023) bsum[blockIdx.x] = incl;
}

__global__ void k_scan2(const int* __restrict__ bsum, int* __restrict__ bbase, int* __restrict__ offs){
  if (blockIdx.x == 0 && threadIdx.x == 0){
    int run = 0;
    for (int b = 0; b < NB1; b++){ int t = bsum[b]; bbase[b] = run; run += t; }
    offs[NNODES] = NEDGES;
  }
}

__global__ void k_scan3(int* __restrict__ offs, const int* __restrict__ bbase, int* __restrict__ cur){
  int n = blockIdx.x*256 + threadIdx.x;
  if (n < NNODES){
    int o = offs[n] + bbase[n >> 10];
    offs[n] = o;
    cur[n]  = o;
  }
}

__global__ void k_scatter(const int* __restrict__ src, const int* __restrict__ tgt,
                          const float* __restrict__ elen, int* cur,
                          int* __restrict__ stgt, float* __restrict__ skey){
  int e = blockIdx.x*256 + threadIdx.x;
  if (e >= NEDGES) return;
  int s = src[e];
  int pos = atomicAdd(&cur[s], 1);
  stgt[pos] = tgt[e];
  float key = (elen[e] - R_MIN_) * ((float)(TBL-1)/(R_MAX_-R_MIN_));
  key = fminf(fmaxf(key, 0.f), (float)(TBL-1) - 1e-3f);
  skey[pos] = key;
}

// ---------------- Gaussian table ----------------
__global__ void k_gauss(const float* __restrict__ Wf, const float* __restrict__ bf,
                        const float* __restrict__ Ws, const float* __restrict__ bs,
                        float* __restrict__ Gt){
  __shared__ float attr[64];
  int bi = blockIdx.x;              // 3*TBL blocks
  int i = bi / TBL, r = bi % TBL;
  int t = threadIdx.x;              // 0..127
  float d = R_MIN_ + (R_MAX_-R_MIN_) * (float)r / (float)(TBL-1);
  if (t < 64){
    float cj = 1.f + 5.f * (float)t / 63.f;
    float u = (d - cj) * (64.f/5.f);
    attr[t] = __expf(-0.5f*u*u);
  }
  __syncthreads();
  int c = t >> 1;
  bool sside = (t & 1);
  const float* W = (sside ? Ws : Wf) + i*192*64 + 128*64 + c;
  float acc = (sside ? bs : bf)[i*64 + c];
  #pragma unroll 8
  for (int j = 0; j < 64; j++) acc = fmaf(attr[j], W[j*64], acc);
  Gt[(i*TBL + r)*128 + t] = acc;
}

// ---------------- Wcat pack ----------------
__global__ void k_wcat(const float* __restrict__ Wf, const float* __restrict__ Ws,
                       float* __restrict__ Wcat){
  int idx = blockIdx.x*256 + threadIdx.x;    // over 3*64*256
  if (idx >= 3*64*256) return;
  int i = idx / (64*256);
  int rem = idx % (64*256);
  int k = rem / 256, c = rem % 256;
  float v;
  if (c < 128){
    int p = c >> 1; bool ss = (c & 1);
    v = (ss ? Ws : Wf)[i*192*64 + k*64 + p];
  } else {
    int p = (c-128) >> 1; bool ss = (c & 1);
    v = (ss ? Ws : Wf)[i*192*64 + (64+k)*64 + p];
  }
  Wcat[i*64*256 + k*256 + c] = v;
}

// ---------------- node transform: tab[n][c] = sum_k x[n][k]*Wc[k][c] ----------------
// LDS-staged: x tile loaded with coalesced float4, read back as wave-broadcast b128.
__global__ void k_ntrans(const float* __restrict__ x, const float* __restrict__ Wc,
                         float* __restrict__ tab){
  __shared__ float xs[16*64];       // 4 KB
  int n0 = blockIdx.x * 16;         // 6250 blocks exact
  int t = threadIdx.x;              // 256 threads
  ((float4*)xs)[t] = ((const float4*)(x + (size_t)n0*64))[t];
  __syncthreads();
  float acc[16];
  #pragma unroll
  for (int nn = 0; nn < 16; nn++) acc[nn] = 0.f;
  #pragma unroll 2
  for (int k = 0; k < 64; k += 4){
    float w0 = Wc[(k+0)*256 + t];
    float w1 = Wc[(k+1)*256 + t];
    float w2 = Wc[(k+2)*256 + t];
    float w3 = Wc[(k+3)*256 + t];
    #pragma unroll
    for (int nn = 0; nn < 16; nn++){
      float4 xv = *(const float4*)(xs + nn*64 + k);
      acc[nn] = fmaf(xv.x, w0, fmaf(xv.y, w1, fmaf(xv.z, w2, fmaf(xv.w, w3, acc[nn]))));
    }
  }
  #pragma unroll
  for (int nn = 0; nn < 16; nn++)
    tab[(size_t)(n0+nn)*256 + t] = acc[nn];
}

// ---------------- edge pass: wave per node; msg accumulate + LN + residual ----------------
__global__ void k_edge(const float* __restrict__ tab, const int* __restrict__ offs,
                       const int* __restrict__ stgt, const float* __restrict__ skey,
                       const float* __restrict__ Gt, const float* __restrict__ lng,
                       const float* __restrict__ lnb, float* __restrict__ x){
  int wid  = (blockIdx.x*256 + threadIdx.x) >> 6;
  int lane = threadIdx.x & 63;
  int n = wid;
  float2 pq = *(const float2*)(tab + (size_t)n*256 + 2*lane);
  float pf = pq.x, ps = pq.y;
  int j0 = offs[n], j1 = offs[n+1];
  float acc = 0.f;
  for (int jb = j0; jb < j1; jb += 64){
    int cnt = min(64, j1 - jb);
    int   t_l = (jb + lane < j1) ? stgt[jb + lane] : 0;
    float k_l = (jb + lane < j1) ? skey[jb + lane] : 0.f;
    for (int u = 0; u < cnt; u++){
      int   tg  = __shfl(t_l, u, 64);
      float key = __shfl(k_l, u, 64);
      int   idx = (int)key;
      float fr  = key - (float)idx;
      float2 q  = *(const float2*)(tab + (size_t)tg*256 + 128 + 2*lane);
      const float* g0 = Gt + (size_t)idx*128 + 2*lane;
      float2 r0 = *(const float2*)(g0);
      float2 r1 = *(const float2*)(g0 + 128);
      float rf = fmaf(fr, r1.x - r0.x, r0.x);
      float rs = fmaf(fr, r1.y - r0.y, r0.y);
      float zf = pf + q.x + rf;
      float zs = ps + q.y + rs;
      acc = fmaf(sigmoid_f(zf), softplus_f(zs), acc);
    }
  }
  float s1 = acc, s2 = acc*acc;
  #pragma unroll
  for (int o = 32; o > 0; o >>= 1){ s1 += __shfl_xor(s1, o, 64); s2 += __shfl_xor(s2, o, 64); }
  float mu  = s1 * (1.f/64.f);
  float var = s2 * (1.f/64.f) - mu*mu;
  float inv = rsqrtf(fmaxf(var, 0.f) + 1e-5f);
  float y = (acc - mu) * inv * lng[lane] + lnb[lane];
  x[(size_t)n*64 + lane] += y;
}

// ---------------- head layer 1: h = softplus(LN(x@W1 + b1)) ----------------
__global__ void k_h1(const float* __restrict__ x, const float* __restrict__ W1,
                     const float* __restrict__ b1, const float* __restrict__ g1,
                     const float* __restrict__ bt1, float* __restrict__ h){
  __shared__ float xs[16*64];       // 4 KB
  __shared__ float r1s[2][2], r2s[2][2];
  int n0 = blockIdx.x * 16;         // 6250 blocks
  int t = threadIdx.x;              // 256 threads
  ((float4*)xs)[t] = ((const float4*)(x + (size_t)n0*64))[t];
  __syncthreads();
  int c = t & 127, g = t >> 7;
  int lane = t & 63, wvp = (t >> 6) & 1;
  float acc[8];
  #pragma unroll
  for (int nn = 0; nn < 8; nn++) acc[nn] = 0.f;
  #pragma unroll 2
  for (int k = 0; k < 64; k += 4){
    float w0 = W1[(k+0)*128 + c];
    float w1 = W1[(k+1)*128 + c];
    float w2 = W1[(k+2)*128 + c];
    float w3 = W1[(k+3)*128 + c];
    #pragma unroll
    for (int nn = 0; nn < 8; nn++){
      float4 xv = *(const float4*)(xs + (g*8+nn)*64 + k);
      acc[nn] = fmaf(xv.x, w0, fmaf(xv.y, w1, fmaf(xv.z, w2, fmaf(xv.w, w3, acc[nn]))));
    }
  }
  float bc = b1[c], gc = g1[c], btc = bt1[c];
  for (int nn = 0; nn < 8; nn++){
    float v = acc[nn] + bc;
    float s1 = v, s2 = v*v;
    #pragma unroll
    for (int o = 32; o > 0; o >>= 1){ s1 += __shfl_xor(s1, o, 64); s2 += __shfl_xor(s2, o, 64); }
    if (lane == 0){ r1s[g][wvp] = s1; r2s[g][wvp] = s2; }
    __syncthreads();
    float t1 = r1s[g][0] + r1s[g][1], t2 = r2s[g][0] + r2s[g][1];
    float mu = t1*(1.f/128.f), var = t2*(1.f/128.f) - mu*mu;
    float inv = rsqrtf(fmaxf(var, 0.f) + 1e-5f);
    float z = (v - mu)*inv*gc + btc;
    h[(size_t)(n0 + g*8 + nn)*128 + c] = softplus_f(z);
    __syncthreads();
  }
}

// ---------------- head layer 2 + output proj + segment sum ----------------
__global__ void k_h2(const float* __restrict__ h, const float* __restrict__ W2,
                     const float* __restrict__ b2, const float* __restrict__ g2,
                     const float* __restrict__ bt2, const float* __restrict__ Wout,
                     const int* __restrict__ batch, float* gsum, int* gcnt){
  __shared__ float hs[16*128];      // 8 KB
  __shared__ float r1s[2][2], r2s[2][2], r3s[2][2];
  int n0 = blockIdx.x * 16;         // 6250 blocks
  int t = threadIdx.x;              // 256 threads
  {
    const float4* hp = (const float4*)(h + (size_t)n0*128);
    ((float4*)hs)[t]       = hp[t];
    ((float4*)hs)[t + 256] = hp[t + 256];
  }
  __syncthreads();
  int c = t & 127, g = t >> 7;
  int lane = t & 63, wvp = (t >> 6) & 1;
  float acc[8];
  #pragma unroll
  for (int nn = 0; nn < 8; nn++) acc[nn] = 0.f;
  #pragma unroll 2
  for (int k = 0; k < 128; k += 4){
    float w0 = W2[(k+0)*128 + c];
    float w1 = W2[(k+1)*128 + c];
    float w2 = W2[(k+2)*128 + c];
    float w3 = W2[(k+3)*128 + c];
    #pragma unroll
    for (int nn = 0; nn < 8; nn++){
      float4 hv = *(const float4*)(hs + (g*8+nn)*128 + k);
      acc[nn] = fmaf(hv.x, w0, fmaf(hv.y, w1, fmaf(hv.z, w2, fmaf(hv.w, w3, acc[nn]))));
    }
  }
  float bc = b2[c], gc = g2[c], btc = bt2[c], wo = Wout[c];
  for (int nn = 0; nn < 8; nn++){
    float v = acc[nn] + bc;
    float s1 = v, s2 = v*v;
    #pragma unroll
    for (int o = 32; o > 0; o >>= 1){ s1 += __shfl_xor(s1, o, 64); s2 += __shfl_xor(s2, o, 64); }
    if (lane == 0){ r1s[g][wvp] = s1; r2s[g][wvp] = s2; }
    __syncthreads();
    float t1 = r1s[g][0] + r1s[g][1], t2 = r2s[g][0] + r2s[g][1];
    float mu = t1*(1.f/128.f), var = t2*(1.f/128.f) - mu*mu;
    float inv = rsqrtf(fmaxf(var, 0.f) + 1e-5f);
    float z = (v - mu)*inv*gc + btc;
    float ev = softplus_f(z) * wo;
    float s3 = ev;
    #pragma unroll
    for (int o = 32; o > 0; o >>= 1) s3 += __shfl_xor(s3, o, 64);
    if (lane == 0) r3s[g][wvp] = s3;
    __syncthreads();
    if ((t & 127) == 0){
      int node = n0 + g*8 + nn;
      int gr = batch[node];
      atomicAdd(&gsum[gr], r3s[g][0] + r3s[g][1]);
      atomicAdd(&gcnt[gr], 1);
    }
  }
}

// ---------------- final: mean per graph ----------------
__global__ void k_final(const float* __restrict__ gsum, const int* __restrict__ gcnt,
                        const float* __restrict__ bout, float* __restrict__ out){
  int g = threadIdx.x;
  if (g < NGRAPH)
    out[g] = gsum[g] / fmaxf((float)gcnt[g], 1.f) + bout[0];
}

extern "C" void kernel_launch(void* const* d_in, const int* in_sizes, int n_in,
                              void* d_out, int out_size, void* d_ws, size_t ws_size,
                              hipStream_t stream){
  const int*   numbers = (const int*)d_in[0];
  const int*   eidx    = (const int*)d_in[1];
  const float* elen    = (const float*)d_in[2];
  const int*   batch   = (const int*)d_in[3];
  const float* embed   = (const float*)d_in[4];
  const float* Wf      = (const float*)d_in[5];
  const float* bf      = (const float*)d_in[6];
  const float* Ws      = (const float*)d_in[7];
  const float* bs      = (const float*)d_in[8];
  const float* lng     = (const float*)d_in[9];
  const float* lnb     = (const float*)d_in[10];
  const float* W1      = (const float*)d_in[11];
  const float* b1      = (const float*)d_in[12];
  const float* g1      = (const float*)d_in[13];
  const float* bt1     = (const float*)d_in[14];
  const float* W2      = (const float*)d_in[15];
  const float* b2      = (const float*)d_in[16];
  const float* g2      = (const float*)d_in[17];
  const float* bt2     = (const float*)d_in[18];
  const float* Wout    = (const float*)d_in[19];
  const float* bout    = (const float*)d_in[20];
  const int* src = eidx;
  const int* tgt = eidx + NEDGES;

  float* x    = (float*)d_ws;                         // N*64
  float* tab  = x    + (size_t)NNODES*64;             // N*256
  float* Gt   = tab  + (size_t)NNODES*256;            // 3*TBL*128
  float* Wcat = Gt   + (size_t)3*TBL*128;             // 3*64*256
  float* skey = Wcat + (size_t)3*64*256;              // E
  int*   stgt = (int*)(skey + NEDGES);                // E
  int*   offs = stgt + NEDGES;                        // N+1
  int*   cur  = offs + NNODES + 1;                    // N
  int*   deg  = cur  + NNODES;                        // N
  int*   bsum = deg  + NNODES;                        // 128
  int*   bbase= bsum + 128;                           // 128
  float* gsum = (float*)(bbase + 128);                // 256
  int*   gcnt = (int*)(gsum + NGRAPH);                // 256
  float* h    = tab;                                  // reuse (N*128 <= N*256)
  float* out  = (float*)d_out;

  k_init  <<<(NNODES+255)/256, 256, 0, stream>>>(deg, gsum, gcnt);
  k_embed <<<(NNODES*64+255)/256, 256, 0, stream>>>(numbers, embed, x);

  k_hist   <<<(NEDGES+255)/256, 256, 0, stream>>>(src, deg);
  k_scan1  <<<NB1, 1024, 0, stream>>>(deg, offs, bsum);
  k_scan2  <<<1, 64, 0, stream>>>(bsum, bbase, offs);
  k_scan3  <<<(NNODES+255)/256, 256, 0, stream>>>(offs, bbase, cur);
  k_scatter<<<(NEDGES+255)/256, 256, 0, stream>>>(src, tgt, elen, cur, stgt, skey);

  k_gauss <<<3*TBL, 128, 0, stream>>>(Wf, bf, Ws, bs, Gt);
  k_wcat  <<<(3*64*256+255)/256, 256, 0, stream>>>(Wf, Ws, Wcat);

  for (int i = 0; i < NCONV; i++){
    k_ntrans<<<NNODES/16, 256, 0, stream>>>(x, Wcat + (size_t)i*64*256, tab);
    k_edge  <<<NNODES/4, 256, 0, stream>>>(tab, offs, stgt, skey,
                                           Gt + (size_t)i*TBL*128,
                                           lng + i*64, lnb + i*64, x);
  }

  k_h1<<<NNODES/16, 256, 0, stream>>>(x, W1, b1, g1, bt1, h);
  k_h2<<<NNODES/16, 256, 0, stream>>>(h, W2, b2, g2, bt2, Wout, batch, gsum, gcnt);
  k_final<<<1, 256, 0, stream>>>(gsum, gcnt, bout, out);
}

// Round 3
// 1259.326 us; speedup vs baseline: 1.1626x; 1.1626x over previous
//
#include <hip/hip_runtime.h>
#include <math.h>

#define NNODES 100000
#define NEDGES 1600000
#define NGRAPH 256
#define NCONV  3
#define TBL    2048
#define NB1    98          // ceil(100000/1024)
#define R_MIN_ 1.0f
#define R_MAX_ 6.0f

__device__ __forceinline__ float softplus_f(float x){
  return fmaxf(x, 0.f) + __logf(1.f + __expf(-fabsf(x)));
}
__device__ __forceinline__ float sigmoid_f(float x){
  return __builtin_amdgcn_rcpf(1.f + __expf(-x));
}
__device__ __forceinline__ void fma4(float4& a, float s, const float4 w){
  a.x = fmaf(s, w.x, a.x); a.y = fmaf(s, w.y, a.y);
  a.z = fmaf(s, w.z, a.z); a.w = fmaf(s, w.w, a.w);
}

// ---------------- init ----------------
__global__ void k_init(int* deg, float* gsum, int* gcnt){
  int i = blockIdx.x*256 + threadIdx.x;
  if (i < NNODES) deg[i] = 0;
  if (i < NGRAPH){ gsum[i] = 0.f; gcnt[i] = 0; }
}

// ---------------- embedding gather ----------------
__global__ void k_embed(const int* __restrict__ numbers, const float* __restrict__ embed,
                        float* __restrict__ x){
  int i = blockIdx.x*256 + threadIdx.x;
  if (i >= NNODES*64) return;
  int n = i >> 6, c = i & 63;
  x[i] = embed[numbers[n]*64 + c];
}

// ---------------- CSR build ----------------
__global__ void k_hist(const int* __restrict__ src, int* deg){
  int e = blockIdx.x*256 + threadIdx.x;
  if (e < NEDGES) atomicAdd(&deg[src[e]], 1);
}

__global__ void k_scan1(const int* __restrict__ deg, int* __restrict__ offs, int* __restrict__ bsum){
  __shared__ int s[1024];
  int n = blockIdx.x*1024 + threadIdx.x;
  int v = (n < NNODES) ? deg[n] : 0;
  s[threadIdx.x] = v;
  __syncthreads();
  for (int d = 1; d < 1024; d <<= 1){
    int t = (threadIdx.x >= d) ? s[threadIdx.x - d] : 0;
    __syncthreads();
    s[threadIdx.x] += t;
    __syncthreads();
  }
  int incl = s[threadIdx.x];
  if (n < NNODES) offs[n] = incl - v;
  if (threadIdx.x == 1023) bsum[blockIdx.x] = incl;
}

__global__ void k_scan2(const int* __restrict__ bsum, int* __restrict__ bbase, int* __restrict__ offs){
  if (blockIdx.x == 0 && threadIdx.x == 0){
    int run = 0;
    for (int b = 0; b < NB1; b++){ int t = bsum[b]; bbase[b] = run; run += t; }
    offs[NNODES] = NEDGES;
  }
}

__global__ void k_scan3(int* __restrict__ offs, const int* __restrict__ bbase, int* __restrict__ cur){
  int n = blockIdx.x*256 + threadIdx.x;
  if (n < NNODES){
    int o = offs[n] + bbase[n >> 10];
    offs[n] = o;
    cur[n]  = o;
  }
}

__global__ void k_scatter(const int* __restrict__ src, const int* __restrict__ tgt,
                          const float* __restrict__ elen, int* cur,
                          int* __restrict__ stgt, float* __restrict__ skey){
  int e = blockIdx.x*256 + threadIdx.x;
  if (e >= NEDGES) return;
  int s = src[e];
  int pos = atomicAdd(&cur[s], 1);
  stgt[pos] = tgt[e];
  float key = (elen[e] - R_MIN_) * ((float)(TBL-1)/(R_MAX_-R_MIN_));
  key = fminf(fmaxf(key, 0.f), (float)(TBL-1) - 1e-3f);
  skey[pos] = key;
}

// ---------------- Gaussian table ----------------
__global__ void k_gauss(const float* __restrict__ Wf, const float* __restrict__ bf,
                        const float* __restrict__ Ws, const float* __restrict__ bs,
                        float* __restrict__ Gt){
  __shared__ float attr[64];
  int bi = blockIdx.x;
  int i = bi / TBL, r = bi % TBL;
  int t = threadIdx.x;
  float d = R_MIN_ + (R_MAX_-R_MIN_) * (float)r / (float)(TBL-1);
  if (t < 64){
    float cj = 1.f + 5.f * (float)t / 63.f;
    float u = (d - cj) * (64.f/5.f);
    attr[t] = __expf(-0.5f*u*u);
  }
  __syncthreads();
  int c = t >> 1;
  bool sside = (t & 1);
  const float* W = (sside ? Ws : Wf) + i*192*64 + 128*64 + c;
  float acc = (sside ? bs : bf)[i*64 + c];
  #pragma unroll 8
  for (int j = 0; j < 64; j++) acc = fmaf(attr[j], W[j*64], acc);
  Gt[(i*TBL + r)*128 + t] = acc;
}

// ---------------- Wcat pack ----------------
__global__ void k_wcat(const float* __restrict__ Wf, const float* __restrict__ Ws,
                       float* __restrict__ Wcat){
  int idx = blockIdx.x*256 + threadIdx.x;
  if (idx >= 3*64*256) return;
  int i = idx / (64*256);
  int rem = idx % (64*256);
  int k = rem / 256, c = rem % 256;
  float v;
  if (c < 128){
    int p = c >> 1; bool ss = (c & 1);
    v = (ss ? Ws : Wf)[i*192*64 + k*64 + p];
  } else {
    int p = (c-128) >> 1; bool ss = (c & 1);
    v = (ss ? Ws : Wf)[i*192*64 + (64+k)*64 + p];
  }
  Wcat[i*64*256 + k*256 + c] = v;
}

// ---------------- node transform: 32 nodes x 256 cols per block ----------------
__global__ void k_ntrans(const float* __restrict__ x, const float* __restrict__ Wc,
                         float* __restrict__ tab){
  __shared__ float xs[32*64];       // 8 KB
  int n0 = blockIdx.x * 32;         // 3125 blocks exact
  int t = threadIdx.x;              // 256
  ((float4*)xs)[t]       = ((const float4*)(x + (size_t)n0*64))[t];
  ((float4*)xs)[t + 256] = ((const float4*)(x + (size_t)n0*64))[t + 256];
  __syncthreads();
  int cg = t & 63, ng = t >> 6;     // 64 col-groups x 4 cols; 4 node-groups x 8 nodes
  float4 acc[8];
  #pragma unroll
  for (int i = 0; i < 8; i++) acc[i] = make_float4(0.f,0.f,0.f,0.f);
  const float* wp = Wc + 4*cg;
  const float* xp = xs + ng*8*64;
  #pragma unroll 2
  for (int k = 0; k < 64; k += 4){
    float4 w0 = *(const float4*)(wp + (k+0)*256);
    float4 w1 = *(const float4*)(wp + (k+1)*256);
    float4 w2 = *(const float4*)(wp + (k+2)*256);
    float4 w3 = *(const float4*)(wp + (k+3)*256);
    #pragma unroll
    for (int nn = 0; nn < 8; nn++){
      float4 xv = *(const float4*)(xp + nn*64 + k);
      fma4(acc[nn], xv.x, w0); fma4(acc[nn], xv.y, w1);
      fma4(acc[nn], xv.z, w2); fma4(acc[nn], xv.w, w3);
    }
  }
  #pragma unroll
  for (int nn = 0; nn < 8; nn++)
    *(float4*)(tab + (size_t)(n0 + ng*8 + nn)*256 + 4*cg) = acc[nn];
}

// ---------------- edge pass: wave per node ----------------
__global__ void k_edge(const float* __restrict__ tab, const int* __restrict__ offs,
                       const int* __restrict__ stgt, const float* __restrict__ skey,
                       const float* __restrict__ Gt, const float* __restrict__ lng,
                       const float* __restrict__ lnb, float* __restrict__ x){
  int wid  = (blockIdx.x*256 + threadIdx.x) >> 6;
  int lane = threadIdx.x & 63;
  int n = wid;
  float2 pq = *(const float2*)(tab + (size_t)n*256 + 2*lane);
  float pf = pq.x, ps = pq.y;
  int j0 = offs[n], j1 = offs[n+1];
  float acc = 0.f;
  for (int jb = j0; jb < j1; jb += 64){
    int cnt = min(64, j1 - jb);
    int   t_l = (jb + lane < j1) ? stgt[jb + lane] : 0;
    float k_l = (jb + lane < j1) ? skey[jb + lane] : 0.f;
    for (int u = 0; u < cnt; u++){
      int   tg  = __shfl(t_l, u, 64);
      float key = __shfl(k_l, u, 64);
      int   idx = (int)key;
      float fr  = key - (float)idx;
      float2 q  = *(const float2*)(tab + (size_t)tg*256 + 128 + 2*lane);
      const float* g0 = Gt + (size_t)idx*128 + 2*lane;
      float2 r0 = *(const float2*)(g0);
      float2 r1 = *(const float2*)(g0 + 128);
      float rf = fmaf(fr, r1.x - r0.x, r0.x);
      float rs = fmaf(fr, r1.y - r0.y, r0.y);
      float zf = pf + q.x + rf;
      float zs = ps + q.y + rs;
      acc = fmaf(sigmoid_f(zf), softplus_f(zs), acc);
    }
  }
  float s1 = acc, s2 = acc*acc;
  #pragma unroll
  for (int o = 32; o > 0; o >>= 1){ s1 += __shfl_xor(s1, o, 64); s2 += __shfl_xor(s2, o, 64); }
  float mu  = s1 * (1.f/64.f);
  float var = s2 * (1.f/64.f) - mu*mu;
  float inv = rsqrtf(fmaxf(var, 0.f) + 1e-5f);
  float y = (acc - mu) * inv * lng[lane] + lnb[lane];
  x[(size_t)n*64 + lane] += y;
}

// ---------------- head layer 1: 32 nodes x 128 cols per block ----------------
__global__ void k_h1(const float* __restrict__ x, const float* __restrict__ W1,
                     const float* __restrict__ b1, const float* __restrict__ g1,
                     const float* __restrict__ bt1, float* __restrict__ h){
  __shared__ float xs[32*64];       // 8 KB
  int n0 = blockIdx.x * 32;         // 3125 blocks
  int t = threadIdx.x;              // 256
  ((float4*)xs)[t]       = ((const float4*)(x + (size_t)n0*64))[t];
  ((float4*)xs)[t + 256] = ((const float4*)(x + (size_t)n0*64))[t + 256];
  __syncthreads();
  int cg = t & 31, ng = t >> 5;     // 32 col-groups x 4 cols; 8 node-groups x 4 nodes
  float4 acc[4];
  #pragma unroll
  for (int i = 0; i < 4; i++) acc[i] = make_float4(0.f,0.f,0.f,0.f);
  const float* wp = W1 + 4*cg;
  const float* xp = xs + ng*4*64;
  #pragma unroll 2
  for (int k = 0; k < 64; k += 4){
    float4 w0 = *(const float4*)(wp + (k+0)*128);
    float4 w1 = *(const float4*)(wp + (k+1)*128);
    float4 w2 = *(const float4*)(wp + (k+2)*128);
    float4 w3 = *(const float4*)(wp + (k+3)*128);
    #pragma unroll
    for (int nn = 0; nn < 4; nn++){
      float4 xv = *(const float4*)(xp + nn*64 + k);
      fma4(acc[nn], xv.x, w0); fma4(acc[nn], xv.y, w1);
      fma4(acc[nn], xv.z, w2); fma4(acc[nn], xv.w, w3);
    }
  }
  float4 bv  = *(const float4*)(b1  + 4*cg);
  float4 gv  = *(const float4*)(g1  + 4*cg);
  float4 btv = *(const float4*)(bt1 + 4*cg);
  #pragma unroll
  for (int nn = 0; nn < 4; nn++){
    float4 v = acc[nn];
    v.x += bv.x; v.y += bv.y; v.z += bv.z; v.w += bv.w;
    float s1 = v.x + v.y + v.z + v.w;
    float s2 = v.x*v.x + v.y*v.y + v.z*v.z + v.w*v.w;
    #pragma unroll
    for (int o = 16; o > 0; o >>= 1){ s1 += __shfl_xor(s1, o, 64); s2 += __shfl_xor(s2, o, 64); }
    float mu  = s1 * (1.f/128.f);
    float var = s2 * (1.f/128.f) - mu*mu;
    float inv = rsqrtf(fmaxf(var, 0.f) + 1e-5f);
    float4 o4;
    o4.x = softplus_f((v.x - mu)*inv*gv.x + btv.x);
    o4.y = softplus_f((v.y - mu)*inv*gv.y + btv.y);
    o4.z = softplus_f((v.z - mu)*inv*gv.z + btv.z);
    o4.w = softplus_f((v.w - mu)*inv*gv.w + btv.w);
    *(float4*)(h + (size_t)(n0 + ng*4 + nn)*128 + 4*cg) = o4;
  }
}

// ---------------- head layer 2 + out proj + segment sum: 32 nodes x 128 cols ----------------
__global__ void k_h2(const float* __restrict__ h, const float* __restrict__ W2,
                     const float* __restrict__ b2, const float* __restrict__ g2,
                     const float* __restrict__ bt2, const float* __restrict__ Wout,
                     const int* __restrict__ batch, float* gsum, int* gcnt){
  __shared__ float hs[32*128];      // 16 KB
  int n0 = blockIdx.x * 32;         // 3125 blocks
  int t = threadIdx.x;              // 256
  {
    const float4* hp = (const float4*)(h + (size_t)n0*128);
    ((float4*)hs)[t]       = hp[t];
    ((float4*)hs)[t + 256] = hp[t + 256];
    ((float4*)hs)[t + 512] = hp[t + 512];
    ((float4*)hs)[t + 768] = hp[t + 768];
  }
  __syncthreads();
  int cg = t & 31, ng = t >> 5;     // 32 col-groups x 4 cols; 8 node-groups x 4 nodes
  float4 acc[4];
  #pragma unroll
  for (int i = 0; i < 4; i++) acc[i] = make_float4(0.f,0.f,0.f,0.f);
  const float* wp = W2 + 4*cg;
  const float* hp = hs + ng*4*128;
  #pragma unroll 2
  for (int k = 0; k < 128; k += 4){
    float4 w0 = *(const float4*)(wp + (k+0)*128);
    float4 w1 = *(const float4*)(wp + (k+1)*128);
    float4 w2 = *(const float4*)(wp + (k+2)*128);
    float4 w3 = *(const float4*)(wp + (k+3)*128);
    #pragma unroll
    for (int nn = 0; nn < 4; nn++){
      float4 hv = *(const float4*)(hp + nn*128 + k);
      fma4(acc[nn], hv.x, w0); fma4(acc[nn], hv.y, w1);
      fma4(acc[nn], hv.z, w2); fma4(acc[nn], hv.w, w3);
    }
  }
  float4 bv  = *(const float4*)(b2  + 4*cg);
  float4 gv  = *(const float4*)(g2  + 4*cg);
  float4 btv = *(const float4*)(bt2 + 4*cg);
  float4 wo  = *(const float4*)(Wout + 4*cg);
  #pragma unroll
  for (int nn = 0; nn < 4; nn++){
    float4 v = acc[nn];
    v.x += bv.x; v.y += bv.y; v.z += bv.z; v.w += bv.w;
    float s1 = v.x + v.y + v.z + v.w;
    float s2 = v.x*v.x + v.y*v.y + v.z*v.z + v.w*v.w;
    #pragma unroll
    for (int o = 16; o > 0; o >>= 1){ s1 += __shfl_xor(s1, o, 64); s2 += __shfl_xor(s2, o, 64); }
    float mu  = s1 * (1.f/128.f);
    float var = s2 * (1.f/128.f) - mu*mu;
    float inv = rsqrtf(fmaxf(var, 0.f) + 1e-5f);
    float ev = softplus_f((v.x - mu)*inv*gv.x + btv.x) * wo.x
             + softplus_f((v.y - mu)*inv*gv.y + btv.y) * wo.y
             + softplus_f((v.z - mu)*inv*gv.z + btv.z) * wo.z
             + softplus_f((v.w - mu)*inv*gv.w + btv.w) * wo.w;
    #pragma unroll
    for (int o = 16; o > 0; o >>= 1) ev += __shfl_xor(ev, o, 64);
    if (cg == 0){
      int node = n0 + ng*4 + nn;
      int gr = batch[node];
      atomicAdd(&gsum[gr], ev);
      atomicAdd(&gcnt[gr], 1);
    }
  }
}

// ---------------- final ----------------
__global__ void k_final(const float* __restrict__ gsum, const int* __restrict__ gcnt,
                        const float* __restrict__ bout, float* __restrict__ out){
  int g = threadIdx.x;
  if (g < NGRAPH)
    out[g] = gsum[g] / fmaxf((float)gcnt[g], 1.f) + bout[0];
}

extern "C" void kernel_launch(void* const* d_in, const int* in_sizes, int n_in,
                              void* d_out, int out_size, void* d_ws, size_t ws_size,
                              hipStream_t stream){
  const int*   numbers = (const int*)d_in[0];
  const int*   eidx    = (const int*)d_in[1];
  const float* elen    = (const float*)d_in[2];
  const int*   batch   = (const int*)d_in[3];
  const float* embed   = (const float*)d_in[4];
  const float* Wf      = (const float*)d_in[5];
  const float* bf      = (const float*)d_in[6];
  const float* Ws      = (const float*)d_in[7];
  const float* bs      = (const float*)d_in[8];
  const float* lng     = (const float*)d_in[9];
  const float* lnb     = (const float*)d_in[10];
  const float* W1      = (const float*)d_in[11];
  const float* b1      = (const float*)d_in[12];
  const float* g1      = (const float*)d_in[13];
  const float* bt1     = (const float*)d_in[14];
  const float* W2      = (const float*)d_in[15];
  const float* b2      = (const float*)d_in[16];
  const float* g2      = (const float*)d_in[17];
  const float* bt2     = (const float*)d_in[18];
  const float* Wout    = (const float*)d_in[19];
  const float* bout    = (const float*)d_in[20];
  const int* src = eidx;
  const int* tgt = eidx + NEDGES;

  float* x    = (float*)d_ws;                         // N*64
  float* tab  = x    + (size_t)NNODES*64;             // N*256
  float* Gt   = tab  + (size_t)NNODES*256;            // 3*TBL*128
  float* Wcat = Gt   + (size_t)3*TBL*128;             // 3*64*256
  float* skey = Wcat + (size_t)3*64*256;              // E
  int*   stgt = (int*)(skey + NEDGES);                // E
  int*   offs = stgt + NEDGES;                        // N+1
  int*   cur  = offs + NNODES + 1;                    // N
  int*   deg  = cur  + NNODES;                        // N
  int*   bsum = deg  + NNODES;                        // 128
  int*   bbase= bsum + 128;                           // 128
  float* gsum = (float*)(bbase + 128);                // 256
  int*   gcnt = (int*)(gsum + NGRAPH);                // 256
  float* h    = tab;                                  // reuse
  float* out  = (float*)d_out;

  k_init  <<<(NNODES+255)/256, 256, 0, stream>>>(deg, gsum, gcnt);
  k_embed <<<(NNODES*64+255)/256, 256, 0, stream>>>(numbers, embed, x);

  k_hist   <<<(NEDGES+255)/256, 256, 0, stream>>>(src, deg);
  k_scan1  <<<NB1, 1024, 0, stream>>>(deg, offs, bsum);
  k_scan2  <<<1, 64, 0, stream>>>(bsum, bbase, offs);
  k_scan3  <<<(NNODES+255)/256, 256, 0, stream>>>(offs, bbase, cur);
  k_scatter<<<(NEDGES+255)/256, 256, 0, stream>>>(src, tgt, elen, cur, stgt, skey);

  k_gauss <<<3*TBL, 128, 0, stream>>>(Wf, bf, Ws, bs, Gt);
  k_wcat  <<<(3*64*256+255)/256, 256, 0, stream>>>(Wf, Ws, Wcat);

  for (int i = 0; i < NCONV; i++){
    k_ntrans<<<NNODES/32, 256, 0, stream>>>(x, Wcat + (size_t)i*64*256, tab);
    k_edge  <<<NNODES/4, 256, 0, stream>>>(tab, offs, stgt, skey,
                                           Gt + (size_t)i*TBL*128,
                                           lng + i*64, lnb + i*64, x);
  }

  k_h1<<<NNODES/32, 256, 0, stream>>>(x, W1, b1, g1, bt1, h);
  k_h2<<<NNODES/32, 256, 0, stream>>>(h, W2, b2, g2, bt2, Wout, batch, gsum, gcnt);
  k_final<<<1, 256, 0, stream>>>(gsum, gcnt, bout, out);
}